// Round 3
// baseline (396.901 us; speedup 1.0000x reference)
//
#include <hip/hip_runtime.h>
#include <hip/hip_bf16.h>

#define NN 50000      // nodes
#define MP 50048      // padded nodes (391 * 128)
#define NF 64         // features
#define NH 512        // hidden
#define NE 800000     // edges

typedef __attribute__((ext_vector_type(8))) short bf16x8;
typedef __attribute__((ext_vector_type(4))) float f32x4;

#define GLOAD16(g, l)                                                        \
    __builtin_amdgcn_global_load_lds(                                        \
        (const __attribute__((address_space(1))) unsigned int*)(g),          \
        (__attribute__((address_space(3))) unsigned int*)(l), 16, 0, 0)

// ---------------------------------------------------------------------------
// detect whether edge_index is int64 (high dwords all zero) or int32
__global__ void detect_idx(const int* __restrict__ ei, int* __restrict__ flag) {
    if (threadIdx.x == 0 && blockIdx.x == 0) {
        int any = 0;
        for (int i = 0; i < 32; ++i) any |= ei[2 * i + 1];
        *flag = (any == 0) ? 1 : 0;   // 1 => int64 layout
    }
}

// ---------------------------------------------------------------------------
// CSR build: histogram of dst
__global__ __launch_bounds__(256) void edge_hist(const void* __restrict__ eiv,
                                                 const int* __restrict__ flag,
                                                 int* __restrict__ deg) {
    int e = blockIdx.x * 256 + threadIdx.x;
    if (e >= NE) return;
    int dst = *flag ? (int)((const long long*)eiv)[NE + e]
                    : ((const int*)eiv)[NE + e];
    atomicAdd(&deg[dst], 1);
}

// single-block exclusive prefix sum over deg[0..NN) -> rowptr, cursor
__global__ __launch_bounds__(256) void scan_deg(const int* __restrict__ deg,
                                                int* __restrict__ rowptr,
                                                int* __restrict__ cursor) {
    __shared__ int partial[256];
    const int CH = (NN + 255) / 256;   // 196
    int tid = threadIdx.x;
    int c0 = tid * CH;
    int c1 = min(c0 + CH, NN);
    int s = 0;
    for (int i = c0; i < c1; ++i) s += deg[i];
    partial[tid] = s;
    __syncthreads();
    for (int off = 1; off < 256; off <<= 1) {
        int v = 0;
        if (tid >= off) v = partial[tid - off];
        __syncthreads();
        if (tid >= off) partial[tid] += v;
        __syncthreads();
    }
    int run = (tid == 0) ? 0 : partial[tid - 1];
    for (int i = c0; i < c1; ++i) {
        rowptr[i] = run;
        cursor[i] = run;
        run += deg[i];
    }
    if (tid == 255) rowptr[NN] = run;
}

// scatter edge sources into CSR slots
__global__ __launch_bounds__(256) void edge_fill(const void* __restrict__ eiv,
                                                 const int* __restrict__ flag,
                                                 int* __restrict__ cursor,
                                                 int* __restrict__ csr) {
    int e = blockIdx.x * 256 + threadIdx.x;
    if (e >= NE) return;
    int src, dst;
    if (*flag) {
        const long long* ei = (const long long*)eiv;
        src = (int)ei[e];
        dst = (int)ei[NE + e];
    } else {
        const int* ei = (const int*)eiv;
        src = ei[e];
        dst = ei[NE + e];
    }
    int pos = atomicAdd(&cursor[dst], 1);
    csr[pos] = src;
}

// gather-sum: h0b[n] = bf16( x[n] + sum_{s in N(n)} x[s] ), padded rows zero.
// 16 lanes per node, float4 per lane covers the 64-feature row.
__global__ __launch_bounds__(256) void gather(const float* __restrict__ x,
                                              const int* __restrict__ rowptr,
                                              const int* __restrict__ csr,
                                              __hip_bfloat16* __restrict__ h0b) {
    int t = blockIdx.x * 256 + threadIdx.x;
    int n = t >> 4;
    int sub = t & 15;
    if (n >= MP) return;
    union { ushort4 u; __hip_bfloat16 h[4]; } o;
    if (n >= NN) {
        o.u = make_ushort4(0, 0, 0, 0);
        *(ushort4*)&h0b[(long long)n * NF + sub * 4] = o.u;
        return;
    }
    float4 acc = *(const float4*)&x[(long long)n * NF + sub * 4];
    int e0 = rowptr[n], e1 = rowptr[n + 1];
    for (int e = e0; e < e1; ++e) {
        int s = csr[e];
        float4 v = *(const float4*)&x[(long long)s * NF + sub * 4];
        acc.x += v.x; acc.y += v.y; acc.z += v.z; acc.w += v.w;
    }
    o.h[0] = __float2bfloat16(acc.x);
    o.h[1] = __float2bfloat16(acc.y);
    o.h[2] = __float2bfloat16(acc.z);
    o.h[3] = __float2bfloat16(acc.w);
    *(ushort4*)&h0b[(long long)n * NF + sub * 4] = o.u;
}

// W [K][N] fp32 -> WT [N][K] bf16
__global__ __launch_bounds__(256) void cvt_wt(const float* __restrict__ W,
                                              __hip_bfloat16* __restrict__ WT,
                                              int K, int N) {
    int t = blockIdx.x * 256 + threadIdx.x;
    if (t >= K * N) return;
    int n = t % N, k = t / N;
    WT[n * K + k] = __float2bfloat16(W[t]);
}

// ---------------------------------------------------------------------------
// bf16 MFMA GEMM (m97 structure): C[MP,512] = A[MP,K] @ BT[512,K]^T + bias
// 128x128 tile, BK=64, 4 waves (2x2), per-wave 64x64 = 4x4 fragments 16x16.
template <int K, bool RELU, bool OUTBF>
__global__ __launch_bounds__(256) void gemm_mfma(const __hip_bfloat16* __restrict__ A,
                                                 const __hip_bfloat16* __restrict__ BT,
                                                 const float* __restrict__ bias,
                                                 void* __restrict__ C) {
    constexpr int BK = 64;
    __shared__ __hip_bfloat16 As[128 * BK];
    __shared__ __hip_bfloat16 Bs[128 * BK];
    const int tid = threadIdx.x;
    const int lane = tid & 63;
    const int w = tid >> 6;          // wave 0..3
    const int wm = w >> 1, wn = w & 1;
    const long long rbase = (long long)blockIdx.x * 128;
    const int nbase = blockIdx.y * 128;

    f32x4 acc[4][4];
#pragma unroll
    for (int i = 0; i < 4; ++i)
#pragma unroll
        for (int j = 0; j < 4; ++j) acc[i][j] = (f32x4){0.f, 0.f, 0.f, 0.f};

    for (int kb = 0; kb < K; kb += BK) {
        const __hip_bfloat16* ga =
            A + (rbase + w * 32 + (lane >> 3)) * (long long)K + kb + (lane & 7) * 8;
        const __hip_bfloat16* gb =
            BT + (long long)(nbase + w * 32 + (lane >> 3)) * K + kb + (lane & 7) * 8;
        __hip_bfloat16* la = As + (w * 32) * BK;   // wave-uniform LDS base
        __hip_bfloat16* lb = Bs + (w * 32) * BK;
#pragma unroll
        for (int t = 0; t < 4; ++t) {
            GLOAD16(ga + (long long)t * 8 * K, la + t * 8 * BK);
            GLOAD16(gb + (long long)t * 8 * K, lb + t * 8 * BK);
        }
        __syncthreads();

#pragma unroll
        for (int ks = 0; ks < 2; ++ks) {
            bf16x8 af[4], bfr[4];
#pragma unroll
            for (int mi = 0; mi < 4; ++mi)
                af[mi] = *(const bf16x8*)&As[(wm * 64 + mi * 16 + (lane & 15)) * BK +
                                            ks * 32 + (lane >> 4) * 8];
#pragma unroll
            for (int ni = 0; ni < 4; ++ni)
                bfr[ni] = *(const bf16x8*)&Bs[(wn * 64 + ni * 16 + (lane & 15)) * BK +
                                             ks * 32 + (lane >> 4) * 8];
#pragma unroll
            for (int mi = 0; mi < 4; ++mi)
#pragma unroll
                for (int ni = 0; ni < 4; ++ni)
                    acc[mi][ni] = __builtin_amdgcn_mfma_f32_16x16x32_bf16(
                        af[mi], bfr[ni], acc[mi][ni], 0, 0, 0);
        }
        __syncthreads();
    }

    // epilogue: C/D layout col=lane&15, row=(lane>>4)*4+reg
    const int col0 = nbase + wn * 64 + (lane & 15);
    const long long row00 = rbase + wm * 64 + (lane >> 4) * 4;
#pragma unroll
    for (int ni = 0; ni < 4; ++ni) {
        int col = col0 + ni * 16;
        float bv = bias[col];
#pragma unroll
        for (int mi = 0; mi < 4; ++mi) {
            long long r0 = row00 + mi * 16;
#pragma unroll
            for (int r = 0; r < 4; ++r) {
                float v = acc[mi][ni][r] + bv;
                if (RELU) v = fmaxf(v, 0.f);
                if (OUTBF)
                    ((__hip_bfloat16*)C)[(r0 + r) * NH + col] = __float2bfloat16(v);
                else
                    ((float*)C)[(r0 + r) * NH + col] = v;
            }
        }
    }
}

// ---------------------------------------------------------------------------
// per-column sum / sumsq partials via atomics. stats[0..511]=sum, [512..1023]=sumsq
__global__ __launch_bounds__(256) void bn_stats(const float* __restrict__ h2,
                                                float* __restrict__ stats) {
    int tid = threadIdx.x;
    long long base = (long long)blockIdx.x * 128;
    int rmax = min(128, NN - (int)base);
    float s0 = 0.f, q0 = 0.f, s1 = 0.f, q1 = 0.f;
    for (int r = 0; r < rmax; ++r) {
        const float* p = h2 + (base + r) * NH;
        float v0 = p[tid];
        float v1 = p[256 + tid];
        s0 += v0; q0 += v0 * v0;
        s1 += v1; q1 += v1 * v1;
    }
    atomicAdd(&stats[tid], s0);
    atomicAdd(&stats[256 + tid], s1);
    atomicAdd(&stats[512 + tid], q0);
    atomicAdd(&stats[768 + tid], q1);
}

// BN(train stats) + ReLU + classifier (512 -> 2) fused; one wave per row
__global__ __launch_bounds__(256) void bn_cls(const float* __restrict__ h2,
                                              const float* __restrict__ stats,
                                              const float* __restrict__ gamma,
                                              const float* __restrict__ beta,
                                              const float* __restrict__ Wc,
                                              const float* __restrict__ bc,
                                              float* __restrict__ out) {
    __shared__ float scale[NH], shift[NH], wc0[NH], wc1[NH];
    int tid = threadIdx.x;
    for (int c = tid; c < NH; c += 256) {
        float mean = stats[c] * (1.0f / NN);
        float var = stats[NH + c] * (1.0f / NN) - mean * mean;
        float rs = rsqrtf(var + 1e-5f);
        float sc = gamma[c] * rs;
        scale[c] = sc;
        shift[c] = beta[c] - mean * sc;
        wc0[c] = Wc[2 * c];
        wc1[c] = Wc[2 * c + 1];
    }
    __syncthreads();
    int lane = tid & 63;
    int wid = blockIdx.x * 4 + (tid >> 6);
    int nw = gridDim.x * 4;
    float bc0 = bc[0], bc1 = bc[1];
    for (int row = wid; row < NN; row += nw) {
        float a0 = 0.f, a1 = 0.f;
#pragma unroll
        for (int kk = 0; kk < 8; ++kk) {
            int k = kk * 64 + lane;
            float v = h2[(long long)row * NH + k];
            float hn = fmaxf(fmaf(v, scale[k], shift[k]), 0.f);
            a0 = fmaf(hn, wc0[k], a0);
            a1 = fmaf(hn, wc1[k], a1);
        }
#pragma unroll
        for (int off = 32; off; off >>= 1) {
            a0 += __shfl_xor(a0, off);
            a1 += __shfl_xor(a1, off);
        }
        if (lane == 0) {
            out[(long long)row * 2 + 0] = a0 + bc0;
            out[(long long)row * 2 + 1] = a1 + bc1;
        }
    }
}

// ---------------------------------------------------------------------------
extern "C" void kernel_launch(void* const* d_in, const int* in_sizes, int n_in,
                              void* d_out, int out_size, void* d_ws, size_t ws_size,
                              hipStream_t stream) {
    const float* x     = (const float*)d_in[0];
    const void*  ei    = d_in[1];
    const float* W1    = (const float*)d_in[2];
    const float* b1    = (const float*)d_in[3];
    const float* W2    = (const float*)d_in[4];
    const float* b2    = (const float*)d_in[5];
    const float* gamma = (const float*)d_in[6];
    const float* beta  = (const float*)d_in[7];
    const float* Wc    = (const float*)d_in[8];
    const float* bc    = (const float*)d_in[9];
    float* out = (float*)d_out;

    // workspace carve-up (256B aligned)
    char* base = (char*)d_ws;
    size_t o = 0;
    auto alloc = [&](size_t bytes) {
        char* p = base + o;
        o = (o + bytes + 255) & ~(size_t)255;
        return p;
    };
    float*          h2     = (float*)alloc((size_t)MP * NH * 4);
    __hip_bfloat16* h0b    = (__hip_bfloat16*)alloc((size_t)MP * NF * 2);
    __hip_bfloat16* h1b    = (__hip_bfloat16*)alloc((size_t)MP * NH * 2);
    __hip_bfloat16* w1t    = (__hip_bfloat16*)alloc((size_t)NH * NF * 2);
    __hip_bfloat16* w2t    = (__hip_bfloat16*)alloc((size_t)NH * NH * 2);
    int*            deg    = (int*)alloc((size_t)NN * 4);
    int*            rowptr = (int*)alloc((size_t)(NN + 1) * 4);
    int*            cursor = (int*)alloc((size_t)NN * 4);
    int*            csr    = (int*)alloc((size_t)NE * 4);
    float*          stats  = (float*)alloc(1024 * 4);
    int*            flag   = (int*)alloc(256);

    hipMemsetAsync(stats, 0, 1024 * sizeof(float), stream);
    hipMemsetAsync(deg, 0, (size_t)NN * 4, stream);
    detect_idx<<<1, 1, 0, stream>>>((const int*)ei, flag);

    // CSR build + gather (replaces atomic scatter)
    edge_hist<<<(NE + 255) / 256, 256, 0, stream>>>(ei, flag, deg);
    scan_deg<<<1, 256, 0, stream>>>(deg, rowptr, cursor);
    edge_fill<<<(NE + 255) / 256, 256, 0, stream>>>(ei, flag, cursor, csr);
    gather<<<(MP * 16 + 255) / 256, 256, 0, stream>>>(x, rowptr, csr, h0b);

    cvt_wt<<<(NF * NH + 255) / 256, 256, 0, stream>>>(W1, w1t, NF, NH);
    cvt_wt<<<(NH * NH + 255) / 256, 256, 0, stream>>>(W2, w2t, NH, NH);

    dim3 g(MP / 128, NH / 128);
    gemm_mfma<NF, true, true><<<g, 256, 0, stream>>>(h0b, w1t, b1, h1b);
    gemm_mfma<NH, false, false><<<g, 256, 0, stream>>>(h1b, w2t, b2, h2);

    bn_stats<<<(NN + 127) / 128, 256, 0, stream>>>(h2, stats);
    bn_cls<<<512, 256, 0, stream>>>(h2, stats, gamma, beta, Wc, bc, out);
}

// Round 4
// 288.072 us; speedup vs baseline: 1.3778x; 1.3778x over previous
//
#include <hip/hip_runtime.h>
#include <hip/hip_bf16.h>

#define NN 50000      // nodes
#define MP 50048      // padded nodes (391 * 128)
#define NF 64         // features
#define NH 512        // hidden
#define NE 800000     // edges
#define NB 196        // scan blocks = ceil(NN/256)

typedef __attribute__((ext_vector_type(8))) short bf16x8;
typedef __attribute__((ext_vector_type(4))) float f32x4;

#define GLOAD16(g, l)                                                        \
    __builtin_amdgcn_global_load_lds(                                        \
        (const __attribute__((address_space(1))) unsigned int*)(g),          \
        (__attribute__((address_space(3))) unsigned int*)(l), 16, 0, 0)

// ---------------------------------------------------------------------------
// detect whether edge_index is int64 (high dwords all zero) or int32
__global__ void detect_idx(const int* __restrict__ ei, int* __restrict__ flag) {
    if (threadIdx.x == 0 && blockIdx.x == 0) {
        int any = 0;
        for (int i = 0; i < 32; ++i) any |= ei[2 * i + 1];
        *flag = (any == 0) ? 1 : 0;   // 1 => int64 layout
    }
}

// ---------------------------------------------------------------------------
// CSR build: histogram of dst
__global__ __launch_bounds__(256) void edge_hist(const void* __restrict__ eiv,
                                                 const int* __restrict__ flag,
                                                 int* __restrict__ deg) {
    int e = blockIdx.x * 256 + threadIdx.x;
    if (e >= NE) return;
    int dst = *flag ? (int)((const long long*)eiv)[NE + e]
                    : ((const int*)eiv)[NE + e];
    atomicAdd(&deg[dst], 1);
}

// parallel scan step 1: per-block exclusive prefix + block sums
__global__ __launch_bounds__(256) void scan_local(const int* __restrict__ deg,
                                                  int* __restrict__ rowptr,
                                                  int* __restrict__ bsum) {
    __shared__ int sm[256];
    int tid = threadIdx.x;
    int i = blockIdx.x * 256 + tid;
    int v = (i < NN) ? deg[i] : 0;
    sm[tid] = v;
    __syncthreads();
    int acc = v;
#pragma unroll
    for (int off = 1; off < 256; off <<= 1) {
        int t = (tid >= off) ? sm[tid - off] : 0;
        __syncthreads();
        acc += t;
        sm[tid] = acc;
        __syncthreads();
    }
    if (i < NN) rowptr[i] = acc - v;           // local exclusive
    if (tid == 255) bsum[blockIdx.x] = acc;    // block total
}

// parallel scan step 2: exclusive scan of the NB block sums (1 block)
__global__ __launch_bounds__(256) void scan_bsum(const int* __restrict__ bsum,
                                                 int* __restrict__ boff) {
    __shared__ int sm[256];
    int tid = threadIdx.x;
    int v = (tid < NB) ? bsum[tid] : 0;
    sm[tid] = v;
    __syncthreads();
    int acc = v;
#pragma unroll
    for (int off = 1; off < 256; off <<= 1) {
        int t = (tid >= off) ? sm[tid - off] : 0;
        __syncthreads();
        acc += t;
        sm[tid] = acc;
        __syncthreads();
    }
    if (tid < NB) boff[tid] = acc - v;         // exclusive
}

// parallel scan step 3: add block offsets, emit rowptr & cursor
__global__ __launch_bounds__(256) void scan_add(int* __restrict__ rowptr,
                                                const int* __restrict__ boff,
                                                int* __restrict__ cursor) {
    int i = blockIdx.x * 256 + threadIdx.x;
    if (i < NN) {
        int r = rowptr[i] + boff[blockIdx.x];
        rowptr[i] = r;
        cursor[i] = r;
    }
    if (i == 0) rowptr[NN] = NE;   // total is the edge count by construction
}

// scatter edge sources into CSR slots
__global__ __launch_bounds__(256) void edge_fill(const void* __restrict__ eiv,
                                                 const int* __restrict__ flag,
                                                 int* __restrict__ cursor,
                                                 int* __restrict__ csr) {
    int e = blockIdx.x * 256 + threadIdx.x;
    if (e >= NE) return;
    int src, dst;
    if (*flag) {
        const long long* ei = (const long long*)eiv;
        src = (int)ei[e];
        dst = (int)ei[NE + e];
    } else {
        const int* ei = (const int*)eiv;
        src = ei[e];
        dst = ei[NE + e];
    }
    int pos = atomicAdd(&cursor[dst], 1);
    csr[pos] = src;
}

// gather-sum: h0b[n] = bf16( x[n] + sum_{s in N(n)} x[s] ), padded rows zero.
// 16 lanes per node, float4 per lane covers the 64-feature row.
__global__ __launch_bounds__(256) void gather(const float* __restrict__ x,
                                              const int* __restrict__ rowptr,
                                              const int* __restrict__ csr,
                                              __hip_bfloat16* __restrict__ h0b) {
    int t = blockIdx.x * 256 + threadIdx.x;
    int n = t >> 4;
    int sub = t & 15;
    if (n >= MP) return;
    union { ushort4 u; __hip_bfloat16 h[4]; } o;
    if (n >= NN) {
        o.u = make_ushort4(0, 0, 0, 0);
        *(ushort4*)&h0b[(long long)n * NF + sub * 4] = o.u;
        return;
    }
    float4 acc = *(const float4*)&x[(long long)n * NF + sub * 4];
    int e0 = rowptr[n], e1 = rowptr[n + 1];
    for (int e = e0; e < e1; ++e) {
        int s = csr[e];
        float4 v = *(const float4*)&x[(long long)s * NF + sub * 4];
        acc.x += v.x; acc.y += v.y; acc.z += v.z; acc.w += v.w;
    }
    o.h[0] = __float2bfloat16(acc.x);
    o.h[1] = __float2bfloat16(acc.y);
    o.h[2] = __float2bfloat16(acc.z);
    o.h[3] = __float2bfloat16(acc.w);
    *(ushort4*)&h0b[(long long)n * NF + sub * 4] = o.u;
}

// W [K][N] fp32 -> WT [N][K] bf16
__global__ __launch_bounds__(256) void cvt_wt(const float* __restrict__ W,
                                              __hip_bfloat16* __restrict__ WT,
                                              int K, int N) {
    int t = blockIdx.x * 256 + threadIdx.x;
    if (t >= K * N) return;
    int n = t % N, k = t / N;
    WT[n * K + k] = __float2bfloat16(W[t]);
}

// ---------------------------------------------------------------------------
// bf16 MFMA GEMM (m97 structure): C[MP,512] = A[MP,K] @ BT[512,K]^T + bias
// 128x128 tile, BK=64, 4 waves (2x2), per-wave 64x64 = 4x4 fragments 16x16.
template <int K, bool RELU, bool OUTBF>
__global__ __launch_bounds__(256) void gemm_mfma(const __hip_bfloat16* __restrict__ A,
                                                 const __hip_bfloat16* __restrict__ BT,
                                                 const float* __restrict__ bias,
                                                 void* __restrict__ C) {
    constexpr int BK = 64;
    __shared__ __hip_bfloat16 As[128 * BK];
    __shared__ __hip_bfloat16 Bs[128 * BK];
    const int tid = threadIdx.x;
    const int lane = tid & 63;
    const int w = tid >> 6;          // wave 0..3
    const int wm = w >> 1, wn = w & 1;
    const long long rbase = (long long)blockIdx.x * 128;
    const int nbase = blockIdx.y * 128;

    f32x4 acc[4][4];
#pragma unroll
    for (int i = 0; i < 4; ++i)
#pragma unroll
        for (int j = 0; j < 4; ++j) acc[i][j] = (f32x4){0.f, 0.f, 0.f, 0.f};

    for (int kb = 0; kb < K; kb += BK) {
        const __hip_bfloat16* ga =
            A + (rbase + w * 32 + (lane >> 3)) * (long long)K + kb + (lane & 7) * 8;
        const __hip_bfloat16* gb =
            BT + (long long)(nbase + w * 32 + (lane >> 3)) * K + kb + (lane & 7) * 8;
        __hip_bfloat16* la = As + (w * 32) * BK;   // wave-uniform LDS base
        __hip_bfloat16* lb = Bs + (w * 32) * BK;
#pragma unroll
        for (int t = 0; t < 4; ++t) {
            GLOAD16(ga + (long long)t * 8 * K, la + t * 8 * BK);
            GLOAD16(gb + (long long)t * 8 * K, lb + t * 8 * BK);
        }
        __syncthreads();

#pragma unroll
        for (int ks = 0; ks < 2; ++ks) {
            bf16x8 af[4], bfr[4];
#pragma unroll
            for (int mi = 0; mi < 4; ++mi)
                af[mi] = *(const bf16x8*)&As[(wm * 64 + mi * 16 + (lane & 15)) * BK +
                                            ks * 32 + (lane >> 4) * 8];
#pragma unroll
            for (int ni = 0; ni < 4; ++ni)
                bfr[ni] = *(const bf16x8*)&Bs[(wn * 64 + ni * 16 + (lane & 15)) * BK +
                                             ks * 32 + (lane >> 4) * 8];
#pragma unroll
            for (int mi = 0; mi < 4; ++mi)
#pragma unroll
                for (int ni = 0; ni < 4; ++ni)
                    acc[mi][ni] = __builtin_amdgcn_mfma_f32_16x16x32_bf16(
                        af[mi], bfr[ni], acc[mi][ni], 0, 0, 0);
        }
        __syncthreads();
    }

    // epilogue: C/D layout col=lane&15, row=(lane>>4)*4+reg
    const int col0 = nbase + wn * 64 + (lane & 15);
    const long long row00 = rbase + wm * 64 + (lane >> 4) * 4;
#pragma unroll
    for (int ni = 0; ni < 4; ++ni) {
        int col = col0 + ni * 16;
        float bv = bias[col];
#pragma unroll
        for (int mi = 0; mi < 4; ++mi) {
            long long r0 = row00 + mi * 16;
#pragma unroll
            for (int r = 0; r < 4; ++r) {
                float v = acc[mi][ni][r] + bv;
                if (RELU) v = fmaxf(v, 0.f);
                if (OUTBF)
                    ((__hip_bfloat16*)C)[(r0 + r) * NH + col] = __float2bfloat16(v);
                else
                    ((float*)C)[(r0 + r) * NH + col] = v;
            }
        }
    }
}

// ---------------------------------------------------------------------------
// per-column sum / sumsq partials via atomics. stats[0..511]=sum, [512..1023]=sumsq
__global__ __launch_bounds__(256) void bn_stats(const float* __restrict__ h2,
                                                float* __restrict__ stats) {
    int tid = threadIdx.x;
    long long base = (long long)blockIdx.x * 128;
    int rmax = min(128, NN - (int)base);
    float s0 = 0.f, q0 = 0.f, s1 = 0.f, q1 = 0.f;
    for (int r = 0; r < rmax; ++r) {
        const float* p = h2 + (base + r) * NH;
        float v0 = p[tid];
        float v1 = p[256 + tid];
        s0 += v0; q0 += v0 * v0;
        s1 += v1; q1 += v1 * v1;
    }
    atomicAdd(&stats[tid], s0);
    atomicAdd(&stats[256 + tid], s1);
    atomicAdd(&stats[512 + tid], q0);
    atomicAdd(&stats[768 + tid], q1);
}

// BN(train stats) + ReLU + classifier (512 -> 2) fused; one wave per row
__global__ __launch_bounds__(256) void bn_cls(const float* __restrict__ h2,
                                              const float* __restrict__ stats,
                                              const float* __restrict__ gamma,
                                              const float* __restrict__ beta,
                                              const float* __restrict__ Wc,
                                              const float* __restrict__ bc,
                                              float* __restrict__ out) {
    __shared__ float scale[NH], shift[NH], wc0[NH], wc1[NH];
    int tid = threadIdx.x;
    for (int c = tid; c < NH; c += 256) {
        float mean = stats[c] * (1.0f / NN);
        float var = stats[NH + c] * (1.0f / NN) - mean * mean;
        float rs = rsqrtf(var + 1e-5f);
        float sc = gamma[c] * rs;
        scale[c] = sc;
        shift[c] = beta[c] - mean * sc;
        wc0[c] = Wc[2 * c];
        wc1[c] = Wc[2 * c + 1];
    }
    __syncthreads();
    int lane = tid & 63;
    int wid = blockIdx.x * 4 + (tid >> 6);
    int nw = gridDim.x * 4;
    float bc0 = bc[0], bc1 = bc[1];
    for (int row = wid; row < NN; row += nw) {
        float a0 = 0.f, a1 = 0.f;
#pragma unroll
        for (int kk = 0; kk < 8; ++kk) {
            int k = kk * 64 + lane;
            float v = h2[(long long)row * NH + k];
            float hn = fmaxf(fmaf(v, scale[k], shift[k]), 0.f);
            a0 = fmaf(hn, wc0[k], a0);
            a1 = fmaf(hn, wc1[k], a1);
        }
#pragma unroll
        for (int off = 32; off; off >>= 1) {
            a0 += __shfl_xor(a0, off);
            a1 += __shfl_xor(a1, off);
        }
        if (lane == 0) {
            out[(long long)row * 2 + 0] = a0 + bc0;
            out[(long long)row * 2 + 1] = a1 + bc1;
        }
    }
}

// ---------------------------------------------------------------------------
extern "C" void kernel_launch(void* const* d_in, const int* in_sizes, int n_in,
                              void* d_out, int out_size, void* d_ws, size_t ws_size,
                              hipStream_t stream) {
    const float* x     = (const float*)d_in[0];
    const void*  ei    = d_in[1];
    const float* W1    = (const float*)d_in[2];
    const float* b1    = (const float*)d_in[3];
    const float* W2    = (const float*)d_in[4];
    const float* b2    = (const float*)d_in[5];
    const float* gamma = (const float*)d_in[6];
    const float* beta  = (const float*)d_in[7];
    const float* Wc    = (const float*)d_in[8];
    const float* bc    = (const float*)d_in[9];
    float* out = (float*)d_out;

    // workspace carve-up (256B aligned)
    char* base = (char*)d_ws;
    size_t o = 0;
    auto alloc = [&](size_t bytes) {
        char* p = base + o;
        o = (o + bytes + 255) & ~(size_t)255;
        return p;
    };
    float*          h2     = (float*)alloc((size_t)MP * NH * 4);
    __hip_bfloat16* h0b    = (__hip_bfloat16*)alloc((size_t)MP * NF * 2);
    __hip_bfloat16* h1b    = (__hip_bfloat16*)alloc((size_t)MP * NH * 2);
    __hip_bfloat16* w1t    = (__hip_bfloat16*)alloc((size_t)NH * NF * 2);
    __hip_bfloat16* w2t    = (__hip_bfloat16*)alloc((size_t)NH * NH * 2);
    int*            deg    = (int*)alloc((size_t)NN * 4);
    int*            rowptr = (int*)alloc((size_t)(NN + 1) * 4);
    int*            cursor = (int*)alloc((size_t)NN * 4);
    int*            csr    = (int*)alloc((size_t)NE * 4);
    int*            bsum   = (int*)alloc((size_t)NB * 4);
    int*            boff   = (int*)alloc((size_t)NB * 4);
    float*          stats  = (float*)alloc(1024 * 4);
    int*            flag   = (int*)alloc(256);

    hipMemsetAsync(stats, 0, 1024 * sizeof(float), stream);
    hipMemsetAsync(deg, 0, (size_t)NN * 4, stream);
    detect_idx<<<1, 1, 0, stream>>>((const int*)ei, flag);

    // CSR build + gather (replaces atomic scatter)
    edge_hist<<<(NE + 255) / 256, 256, 0, stream>>>(ei, flag, deg);
    scan_local<<<NB, 256, 0, stream>>>(deg, rowptr, bsum);
    scan_bsum<<<1, 256, 0, stream>>>(bsum, boff);
    scan_add<<<NB, 256, 0, stream>>>(rowptr, boff, cursor);
    edge_fill<<<(NE + 255) / 256, 256, 0, stream>>>(ei, flag, cursor, csr);
    gather<<<(MP * 16 + 255) / 256, 256, 0, stream>>>(x, rowptr, csr, h0b);

    cvt_wt<<<(NF * NH + 255) / 256, 256, 0, stream>>>(W1, w1t, NF, NH);
    cvt_wt<<<(NH * NH + 255) / 256, 256, 0, stream>>>(W2, w2t, NH, NH);

    dim3 g(MP / 128, NH / 128);
    gemm_mfma<NF, true, true><<<g, 256, 0, stream>>>(h0b, w1t, b1, h1b);
    gemm_mfma<NH, false, false><<<g, 256, 0, stream>>>(h1b, w2t, b2, h2);

    bn_stats<<<(NN + 127) / 128, 256, 0, stream>>>(h2, stats);
    bn_cls<<<512, 256, 0, stream>>>(h2, stats, gamma, beta, Wc, bc, out);
}

// Round 5
// 284.329 us; speedup vs baseline: 1.3959x; 1.0132x over previous
//
#include <hip/hip_runtime.h>
#include <hip/hip_bf16.h>

#define NN 50000      // nodes
#define MP 50048      // padded nodes (391 * 128)
#define NF 64         // features
#define NH 512        // hidden
#define NE 800000     // edges
#define NB 196        // scan blocks = ceil(NN/256)
#define MB 391        // M blocks = MP/128

typedef __attribute__((ext_vector_type(8))) short bf16x8;
typedef __attribute__((ext_vector_type(4))) float f32x4;

#define GLOAD16(g, l)                                                        \
    __builtin_amdgcn_global_load_lds(                                        \
        (const __attribute__((address_space(1))) unsigned int*)(g),          \
        (__attribute__((address_space(3))) unsigned int*)(l), 16, 0, 0)

// ---------------------------------------------------------------------------
// detect whether edge_index is int64 (high dwords all zero) or int32
__global__ void detect_idx(const int* __restrict__ ei, int* __restrict__ flag) {
    if (threadIdx.x == 0 && blockIdx.x == 0) {
        int any = 0;
        for (int i = 0; i < 32; ++i) any |= ei[2 * i + 1];
        *flag = (any == 0) ? 1 : 0;   // 1 => int64 layout
    }
}

// ---------------------------------------------------------------------------
// CSR build: histogram of dst
__global__ __launch_bounds__(256) void edge_hist(const void* __restrict__ eiv,
                                                 const int* __restrict__ flag,
                                                 int* __restrict__ deg) {
    int e = blockIdx.x * 256 + threadIdx.x;
    if (e >= NE) return;
    int dst = *flag ? (int)((const long long*)eiv)[NE + e]
                    : ((const int*)eiv)[NE + e];
    atomicAdd(&deg[dst], 1);
}

// parallel scan step 1: per-block exclusive prefix + block sums
__global__ __launch_bounds__(256) void scan_local(const int* __restrict__ deg,
                                                  int* __restrict__ rowptr,
                                                  int* __restrict__ bsum) {
    __shared__ int sm[256];
    int tid = threadIdx.x;
    int i = blockIdx.x * 256 + tid;
    int v = (i < NN) ? deg[i] : 0;
    sm[tid] = v;
    __syncthreads();
    int acc = v;
#pragma unroll
    for (int off = 1; off < 256; off <<= 1) {
        int t = (tid >= off) ? sm[tid - off] : 0;
        __syncthreads();
        acc += t;
        sm[tid] = acc;
        __syncthreads();
    }
    if (i < NN) rowptr[i] = acc - v;           // local exclusive
    if (tid == 255) bsum[blockIdx.x] = acc;    // block total
}

// parallel scan step 2: exclusive scan of the NB block sums (1 block)
__global__ __launch_bounds__(256) void scan_bsum(const int* __restrict__ bsum,
                                                 int* __restrict__ boff) {
    __shared__ int sm[256];
    int tid = threadIdx.x;
    int v = (tid < NB) ? bsum[tid] : 0;
    sm[tid] = v;
    __syncthreads();
    int acc = v;
#pragma unroll
    for (int off = 1; off < 256; off <<= 1) {
        int t = (tid >= off) ? sm[tid - off] : 0;
        __syncthreads();
        acc += t;
        sm[tid] = acc;
        __syncthreads();
    }
    if (tid < NB) boff[tid] = acc - v;         // exclusive
}

// parallel scan step 3: add block offsets, emit rowptr & cursor
__global__ __launch_bounds__(256) void scan_add(int* __restrict__ rowptr,
                                                const int* __restrict__ boff,
                                                int* __restrict__ cursor) {
    int i = blockIdx.x * 256 + threadIdx.x;
    if (i < NN) {
        int r = rowptr[i] + boff[blockIdx.x];
        rowptr[i] = r;
        cursor[i] = r;
    }
    if (i == 0) rowptr[NN] = NE;   // total is the edge count by construction
}

// scatter edge sources into CSR slots
__global__ __launch_bounds__(256) void edge_fill(const void* __restrict__ eiv,
                                                 const int* __restrict__ flag,
                                                 int* __restrict__ cursor,
                                                 int* __restrict__ csr) {
    int e = blockIdx.x * 256 + threadIdx.x;
    if (e >= NE) return;
    int src, dst;
    if (*flag) {
        const long long* ei = (const long long*)eiv;
        src = (int)ei[e];
        dst = (int)ei[NE + e];
    } else {
        const int* ei = (const int*)eiv;
        src = ei[e];
        dst = ei[NE + e];
    }
    int pos = atomicAdd(&cursor[dst], 1);
    csr[pos] = src;
}

// gather-sum: h0b[n] = bf16( x[n] + sum_{s in N(n)} x[s] ), padded rows zero.
__global__ __launch_bounds__(256) void gather(const float* __restrict__ x,
                                              const int* __restrict__ rowptr,
                                              const int* __restrict__ csr,
                                              __hip_bfloat16* __restrict__ h0b) {
    int t = blockIdx.x * 256 + threadIdx.x;
    int n = t >> 4;
    int sub = t & 15;
    if (n >= MP) return;
    union { ushort4 u; __hip_bfloat16 h[4]; } o;
    if (n >= NN) {
        o.u = make_ushort4(0, 0, 0, 0);
        *(ushort4*)&h0b[(long long)n * NF + sub * 4] = o.u;
        return;
    }
    float4 acc = *(const float4*)&x[(long long)n * NF + sub * 4];
    int e0 = rowptr[n], e1 = rowptr[n + 1];
    for (int e = e0; e < e1; ++e) {
        int s = csr[e];
        float4 v = *(const float4*)&x[(long long)s * NF + sub * 4];
        acc.x += v.x; acc.y += v.y; acc.z += v.z; acc.w += v.w;
    }
    o.h[0] = __float2bfloat16(acc.x);
    o.h[1] = __float2bfloat16(acc.y);
    o.h[2] = __float2bfloat16(acc.z);
    o.h[3] = __float2bfloat16(acc.w);
    *(ushort4*)&h0b[(long long)n * NF + sub * 4] = o.u;
}

// W [K][N] fp32 -> WT [N][K] bf16
__global__ __launch_bounds__(256) void cvt_wt(const float* __restrict__ W,
                                              __hip_bfloat16* __restrict__ WT,
                                              int K, int N) {
    int t = blockIdx.x * 256 + threadIdx.x;
    if (t >= K * N) return;
    int n = t % N, k = t / N;
    WT[n * K + k] = __float2bfloat16(W[t]);
}

// ---------------------------------------------------------------------------
// bf16 MFMA GEMM with LDS XOR-swizzle, inner N-block loop (A L2 reuse) and
// optional fused per-column statistics (for BatchNorm).
// C is always bf16. partial[mb*1024 + {0..511}=sum, {512..1023}=sumsq].
template <int K, int NBL, bool RELU, bool STATS>
__global__ __launch_bounds__(256) void gemm_mfma(const __hip_bfloat16* __restrict__ A,
                                                 const __hip_bfloat16* __restrict__ BT,
                                                 const float* __restrict__ bias,
                                                 __hip_bfloat16* __restrict__ C,
                                                 float* __restrict__ partial) {
    constexpr int BK = 64;
    __shared__ __hip_bfloat16 As[128 * BK];
    __shared__ __hip_bfloat16 Bs[128 * BK];
    __shared__ float smsum[128], smsq[128];
    const int tid = threadIdx.x;
    const int lane = tid & 63;
    const int w = tid >> 6;          // wave 0..3
    const int wm = w >> 1, wn = w & 1;
    const long long rbase = (long long)blockIdx.x * 128;
    const int r8  = lane >> 3;            // stage row within 8-row group = swizzle key
    const int swc = (lane & 7) ^ r8;      // pre-swizzled global chunk (rule #21)
    const int key = lane & 7;             // read-side swizzle key (= row & 7)
    const int hi  = lane >> 4;

    for (int nb = 0; nb < NBL; ++nb) {
        const int nbase = (NBL == 1 ? blockIdx.y : nb) * 128;
        f32x4 acc[4][4];
#pragma unroll
        for (int i = 0; i < 4; ++i)
#pragma unroll
            for (int j = 0; j < 4; ++j) acc[i][j] = (f32x4){0.f, 0.f, 0.f, 0.f};

        for (int kb = 0; kb < K; kb += BK) {
            // stage with pre-swizzled global source; LDS dest stays linear
            const __hip_bfloat16* ga =
                A + (rbase + w * 32 + r8) * (long long)K + kb + swc * 8;
            const __hip_bfloat16* gb =
                BT + (long long)(nbase + w * 32 + r8) * K + kb + swc * 8;
            __hip_bfloat16* la = As + (w * 32) * BK;
            __hip_bfloat16* lb = Bs + (w * 32) * BK;
#pragma unroll
            for (int t = 0; t < 4; ++t) {
                GLOAD16(ga + (long long)t * 8 * K, la + t * 8 * BK);
                GLOAD16(gb + (long long)t * 8 * K, lb + t * 8 * BK);
            }
            __syncthreads();

#pragma unroll
            for (int ks = 0; ks < 2; ++ks) {
                bf16x8 af[4], bfr[4];
#pragma unroll
                for (int mi = 0; mi < 4; ++mi)
                    af[mi] = *(const bf16x8*)&As[(wm * 64 + mi * 16 + (lane & 15)) * BK +
                                                 (((ks * 4 + hi) ^ key) * 8)];
#pragma unroll
                for (int ni = 0; ni < 4; ++ni)
                    bfr[ni] = *(const bf16x8*)&Bs[(wn * 64 + ni * 16 + (lane & 15)) * BK +
                                                  (((ks * 4 + hi) ^ key) * 8)];
#pragma unroll
                for (int mi = 0; mi < 4; ++mi)
#pragma unroll
                    for (int ni = 0; ni < 4; ++ni)
                        acc[mi][ni] = __builtin_amdgcn_mfma_f32_16x16x32_bf16(
                            af[mi], bfr[ni], acc[mi][ni], 0, 0, 0);
            }
            __syncthreads();
        }

        // epilogue: C/D layout col=lane&15, row=hi*4+reg
        if (STATS) {
            if (tid < 128) { smsum[tid] = 0.f; smsq[tid] = 0.f; }
            __syncthreads();
        }
        const int col0 = nbase + wn * 64 + (lane & 15);
        const long long row00 = rbase + wm * 64 + hi * 4;
#pragma unroll
        for (int ni = 0; ni < 4; ++ni) {
            int col = col0 + ni * 16;
            float bv = bias[col];
            float s = 0.f, q = 0.f;
#pragma unroll
            for (int mi = 0; mi < 4; ++mi) {
                long long r0 = row00 + mi * 16;
#pragma unroll
                for (int r = 0; r < 4; ++r) {
                    float v = acc[mi][ni][r] + bv;
                    if (RELU) v = fmaxf(v, 0.f);
                    C[(r0 + r) * NH + col] = __float2bfloat16(v);
                    if (STATS && (r0 + r) < NN) { s += v; q += v * v; }
                }
            }
            if (STATS) {
                s += __shfl_xor(s, 16); s += __shfl_xor(s, 32);
                q += __shfl_xor(q, 16); q += __shfl_xor(q, 32);
                if (lane < 16) {
                    atomicAdd(&smsum[wn * 64 + ni * 16 + lane], s);
                    atomicAdd(&smsq[wn * 64 + ni * 16 + lane], q);
                }
            }
        }
        if (STATS) {
            __syncthreads();
            if (tid < 128) {
                partial[blockIdx.x * 1024 + nb * 128 + tid] = smsum[tid];
                partial[blockIdx.x * 1024 + 512 + nb * 128 + tid] = smsq[tid];
            }
        }
    }
}

// reduce per-block partials: stats[j] = sum_mb partial[mb*1024 + j], j<1024
__global__ __launch_bounds__(256) void stats_reduce(const float* __restrict__ partial,
                                                    float* __restrict__ stats) {
    int j = blockIdx.x * 256 + threadIdx.x;   // 0..1023
    float s = 0.f;
    for (int mb = 0; mb < MB; ++mb) s += partial[mb * 1024 + j];
    stats[j] = s;
}

// BN(train stats) + ReLU + classifier fused; bf16 h2, per-lane register params
__global__ __launch_bounds__(256) void bn_cls(const __hip_bfloat16* __restrict__ h2b,
                                              const float* __restrict__ stats,
                                              const float* __restrict__ gamma,
                                              const float* __restrict__ beta,
                                              const float* __restrict__ Wc,
                                              const float* __restrict__ bc,
                                              float* __restrict__ out) {
    int tid = threadIdx.x;
    int lane = tid & 63;
    int k0 = lane * 8;
    float sc[8], sh[8], w0[8], w1[8];
#pragma unroll
    for (int j = 0; j < 8; ++j) {
        int k = k0 + j;
        float mean = stats[k] * (1.0f / NN);
        float var = stats[512 + k] * (1.0f / NN) - mean * mean;
        float rs = rsqrtf(var + 1e-5f);
        float s = gamma[k] * rs;
        sc[j] = s;
        sh[j] = beta[k] - mean * s;
        w0[j] = Wc[2 * k];
        w1[j] = Wc[2 * k + 1];
    }
    float bc0 = bc[0], bc1 = bc[1];
    int wid = blockIdx.x * 4 + (tid >> 6);
    int nw = gridDim.x * 4;
    for (int row = wid; row < NN; row += nw) {
        bf16x8 v8 = *(const bf16x8*)&h2b[(long long)row * NH + k0];
        float a0 = 0.f, a1 = 0.f;
#pragma unroll
        for (int j = 0; j < 8; ++j) {
            float v = __bfloat162float(((const __hip_bfloat16*)&v8)[j]);
            float hn = fmaxf(fmaf(v, sc[j], sh[j]), 0.f);
            a0 = fmaf(hn, w0[j], a0);
            a1 = fmaf(hn, w1[j], a1);
        }
#pragma unroll
        for (int off = 32; off; off >>= 1) {
            a0 += __shfl_xor(a0, off);
            a1 += __shfl_xor(a1, off);
        }
        if (lane == 0) {
            out[(long long)row * 2 + 0] = a0 + bc0;
            out[(long long)row * 2 + 1] = a1 + bc1;
        }
    }
}

// ---------------------------------------------------------------------------
extern "C" void kernel_launch(void* const* d_in, const int* in_sizes, int n_in,
                              void* d_out, int out_size, void* d_ws, size_t ws_size,
                              hipStream_t stream) {
    const float* x     = (const float*)d_in[0];
    const void*  ei    = d_in[1];
    const float* W1    = (const float*)d_in[2];
    const float* b1    = (const float*)d_in[3];
    const float* W2    = (const float*)d_in[4];
    const float* b2    = (const float*)d_in[5];
    const float* gamma = (const float*)d_in[6];
    const float* beta  = (const float*)d_in[7];
    const float* Wc    = (const float*)d_in[8];
    const float* bc    = (const float*)d_in[9];
    float* out = (float*)d_out;

    // workspace carve-up (256B aligned)
    char* base = (char*)d_ws;
    size_t o = 0;
    auto alloc = [&](size_t bytes) {
        char* p = base + o;
        o = (o + bytes + 255) & ~(size_t)255;
        return p;
    };
    __hip_bfloat16* h0b     = (__hip_bfloat16*)alloc((size_t)MP * NF * 2);
    __hip_bfloat16* h1b     = (__hip_bfloat16*)alloc((size_t)MP * NH * 2);
    __hip_bfloat16* h2b     = (__hip_bfloat16*)alloc((size_t)MP * NH * 2);
    __hip_bfloat16* w1t     = (__hip_bfloat16*)alloc((size_t)NH * NF * 2);
    __hip_bfloat16* w2t     = (__hip_bfloat16*)alloc((size_t)NH * NH * 2);
    int*            deg     = (int*)alloc((size_t)NN * 4);
    int*            rowptr  = (int*)alloc((size_t)(NN + 1) * 4);
    int*            cursor  = (int*)alloc((size_t)NN * 4);
    int*            csr     = (int*)alloc((size_t)NE * 4);
    int*            bsum    = (int*)alloc((size_t)NB * 4);
    int*            boff    = (int*)alloc((size_t)NB * 4);
    float*          partial = (float*)alloc((size_t)MB * 1024 * 4);
    float*          stats   = (float*)alloc(1024 * 4);
    int*            flag    = (int*)alloc(256);

    hipMemsetAsync(deg, 0, (size_t)NN * 4, stream);
    detect_idx<<<1, 1, 0, stream>>>((const int*)ei, flag);

    // CSR build + gather
    edge_hist<<<(NE + 255) / 256, 256, 0, stream>>>(ei, flag, deg);
    scan_local<<<NB, 256, 0, stream>>>(deg, rowptr, bsum);
    scan_bsum<<<1, 256, 0, stream>>>(bsum, boff);
    scan_add<<<NB, 256, 0, stream>>>(rowptr, boff, cursor);
    edge_fill<<<(NE + 255) / 256, 256, 0, stream>>>(ei, flag, cursor, csr);
    gather<<<(MP * 16 + 255) / 256, 256, 0, stream>>>(x, rowptr, csr, h0b);

    cvt_wt<<<(NF * NH + 255) / 256, 256, 0, stream>>>(W1, w1t, NF, NH);
    cvt_wt<<<(NH * NH + 255) / 256, 256, 0, stream>>>(W2, w2t, NH, NH);

    // GEMM1: grid (MB,4); GEMM2: grid (MB) with inner nb loop + fused stats
    dim3 g1(MB, 4);
    gemm_mfma<NF, 1, true, false><<<g1, 256, 0, stream>>>(h0b, w1t, b1, h1b, nullptr);
    gemm_mfma<NH, 4, false, true><<<MB, 256, 0, stream>>>(h1b, w2t, b2, h2b, partial);

    stats_reduce<<<4, 256, 0, stream>>>(partial, stats);
    bn_cls<<<512, 256, 0, stream>>>(h2b, stats, gamma, beta, Wc, bc, out);
}

// Round 6
// 250.647 us; speedup vs baseline: 1.5835x; 1.1344x over previous
//
#include <hip/hip_runtime.h>
#include <hip/hip_bf16.h>

#define NN 50000      // nodes
#define MP 50048      // padded nodes (391 * 128)
#define NF 64         // features
#define NH 512        // hidden
#define NE 800000     // edges
#define NB 196        // scan blocks = ceil(NN/256)
#define MB 391        // M blocks = MP/128

typedef __attribute__((ext_vector_type(8))) short bf16x8;
typedef __attribute__((ext_vector_type(4))) float f32x4;

#define GLOAD16(g, l)                                                        \
    __builtin_amdgcn_global_load_lds(                                        \
        (const __attribute__((address_space(1))) unsigned int*)(g),          \
        (__attribute__((address_space(3))) unsigned int*)(l), 16, 0, 0)

// ---------------------------------------------------------------------------
// detect whether edge_index is int64 (high dwords all zero) or int32
__global__ void detect_idx(const int* __restrict__ ei, int* __restrict__ flag) {
    if (threadIdx.x == 0 && blockIdx.x == 0) {
        int any = 0;
        for (int i = 0; i < 32; ++i) any |= ei[2 * i + 1];
        *flag = (any == 0) ? 1 : 0;   // 1 => int64 layout
    }
}

// ---------------------------------------------------------------------------
// CSR build: histogram of dst
__global__ __launch_bounds__(256) void edge_hist(const void* __restrict__ eiv,
                                                 const int* __restrict__ flag,
                                                 int* __restrict__ deg) {
    int e = blockIdx.x * 256 + threadIdx.x;
    if (e >= NE) return;
    int dst = *flag ? (int)((const long long*)eiv)[NE + e]
                    : ((const int*)eiv)[NE + e];
    atomicAdd(&deg[dst], 1);
}

// parallel scan step 1: per-block exclusive prefix + block sums
__global__ __launch_bounds__(256) void scan_local(const int* __restrict__ deg,
                                                  int* __restrict__ rowptr,
                                                  int* __restrict__ bsum) {
    __shared__ int sm[256];
    int tid = threadIdx.x;
    int i = blockIdx.x * 256 + tid;
    int v = (i < NN) ? deg[i] : 0;
    sm[tid] = v;
    __syncthreads();
    int acc = v;
#pragma unroll
    for (int off = 1; off < 256; off <<= 1) {
        int t = (tid >= off) ? sm[tid - off] : 0;
        __syncthreads();
        acc += t;
        sm[tid] = acc;
        __syncthreads();
    }
    if (i < NN) rowptr[i] = acc - v;           // local exclusive
    if (tid == 255) bsum[blockIdx.x] = acc;    // block total
}

// parallel scan step 2: exclusive scan of the NB block sums (1 block)
__global__ __launch_bounds__(256) void scan_bsum(const int* __restrict__ bsum,
                                                 int* __restrict__ boff) {
    __shared__ int sm[256];
    int tid = threadIdx.x;
    int v = (tid < NB) ? bsum[tid] : 0;
    sm[tid] = v;
    __syncthreads();
    int acc = v;
#pragma unroll
    for (int off = 1; off < 256; off <<= 1) {
        int t = (tid >= off) ? sm[tid - off] : 0;
        __syncthreads();
        acc += t;
        sm[tid] = acc;
        __syncthreads();
    }
    if (tid < NB) boff[tid] = acc - v;         // exclusive
}

// parallel scan step 3: add block offsets, emit rowptr & cursor
__global__ __launch_bounds__(256) void scan_add(int* __restrict__ rowptr,
                                                const int* __restrict__ boff,
                                                int* __restrict__ cursor) {
    int i = blockIdx.x * 256 + threadIdx.x;
    if (i < NN) {
        int r = rowptr[i] + boff[blockIdx.x];
        rowptr[i] = r;
        cursor[i] = r;
    }
    if (i == 0) rowptr[NN] = NE;   // total is the edge count by construction
}

// scatter edge sources into CSR slots
__global__ __launch_bounds__(256) void edge_fill(const void* __restrict__ eiv,
                                                 const int* __restrict__ flag,
                                                 int* __restrict__ cursor,
                                                 int* __restrict__ csr) {
    int e = blockIdx.x * 256 + threadIdx.x;
    if (e >= NE) return;
    int src, dst;
    if (*flag) {
        const long long* ei = (const long long*)eiv;
        src = (int)ei[e];
        dst = (int)ei[NE + e];
    } else {
        const int* ei = (const int*)eiv;
        src = ei[e];
        dst = ei[NE + e];
    }
    int pos = atomicAdd(&cursor[dst], 1);
    csr[pos] = src;
}

// gather-sum: h0b[n] = bf16( x[n] + sum_{s in N(n)} x[s] ), padded rows zero.
__global__ __launch_bounds__(256) void gather(const float* __restrict__ x,
                                              const int* __restrict__ rowptr,
                                              const int* __restrict__ csr,
                                              __hip_bfloat16* __restrict__ h0b) {
    int t = blockIdx.x * 256 + threadIdx.x;
    int n = t >> 4;
    int sub = t & 15;
    if (n >= MP) return;
    union { ushort4 u; __hip_bfloat16 h[4]; } o;
    if (n >= NN) {
        o.u = make_ushort4(0, 0, 0, 0);
        *(ushort4*)&h0b[(long long)n * NF + sub * 4] = o.u;
        return;
    }
    float4 acc = *(const float4*)&x[(long long)n * NF + sub * 4];
    int e0 = rowptr[n], e1 = rowptr[n + 1];
    for (int e = e0; e < e1; ++e) {
        int s = csr[e];
        float4 v = *(const float4*)&x[(long long)s * NF + sub * 4];
        acc.x += v.x; acc.y += v.y; acc.z += v.z; acc.w += v.w;
    }
    o.h[0] = __float2bfloat16(acc.x);
    o.h[1] = __float2bfloat16(acc.y);
    o.h[2] = __float2bfloat16(acc.z);
    o.h[3] = __float2bfloat16(acc.w);
    *(ushort4*)&h0b[(long long)n * NF + sub * 4] = o.u;
}

// W [K][N] fp32 -> WT [N][K] bf16
__global__ __launch_bounds__(256) void cvt_wt(const float* __restrict__ W,
                                              __hip_bfloat16* __restrict__ WT,
                                              int K, int N) {
    int t = blockIdx.x * 256 + threadIdx.x;
    if (t >= K * N) return;
    int n = t % N, k = t / N;
    WT[n * K + k] = __float2bfloat16(W[t]);
}

// ---------------------------------------------------------------------------
// bf16 MFMA GEMM, LDS XOR-swizzled reads (conflict-free), grid (MB, NH/128).
// Optional fused per-column statistics: block (mb,nb) owns cols nb*128..+127,
// writes sums to partial[mb*1024 + col] and sumsq to partial[mb*1024+512+col].
template <int K, bool RELU, bool STATS>
__global__ __launch_bounds__(256) void gemm_mfma(const __hip_bfloat16* __restrict__ A,
                                                 const __hip_bfloat16* __restrict__ BT,
                                                 const float* __restrict__ bias,
                                                 __hip_bfloat16* __restrict__ C,
                                                 float* __restrict__ partial) {
    constexpr int BK = 64;
    __shared__ __hip_bfloat16 As[128 * BK];
    __shared__ __hip_bfloat16 Bs[128 * BK];
    __shared__ float smsum[128], smsq[128];
    const int tid = threadIdx.x;
    const int lane = tid & 63;
    const int w = tid >> 6;          // wave 0..3
    const int wm = w >> 1, wn = w & 1;
    const long long rbase = (long long)blockIdx.x * 128;
    const int nbase = blockIdx.y * 128;
    const int r8  = lane >> 3;            // stage row within 8-row group = swizzle key
    const int swc = (lane & 7) ^ r8;      // pre-swizzled global chunk (rule #21)
    const int key = lane & 7;             // read-side swizzle key (= row & 7)
    const int hi  = lane >> 4;

    f32x4 acc[4][4];
#pragma unroll
    for (int i = 0; i < 4; ++i)
#pragma unroll
        for (int j = 0; j < 4; ++j) acc[i][j] = (f32x4){0.f, 0.f, 0.f, 0.f};

    for (int kb = 0; kb < K; kb += BK) {
        // stage with pre-swizzled global source; LDS dest stays linear
        const __hip_bfloat16* ga =
            A + (rbase + w * 32 + r8) * (long long)K + kb + swc * 8;
        const __hip_bfloat16* gb =
            BT + (long long)(nbase + w * 32 + r8) * K + kb + swc * 8;
        __hip_bfloat16* la = As + (w * 32) * BK;
        __hip_bfloat16* lb = Bs + (w * 32) * BK;
#pragma unroll
        for (int t = 0; t < 4; ++t) {
            GLOAD16(ga + (long long)t * 8 * K, la + t * 8 * BK);
            GLOAD16(gb + (long long)t * 8 * K, lb + t * 8 * BK);
        }
        __syncthreads();

#pragma unroll
        for (int ks = 0; ks < 2; ++ks) {
            bf16x8 af[4], bfr[4];
#pragma unroll
            for (int mi = 0; mi < 4; ++mi)
                af[mi] = *(const bf16x8*)&As[(wm * 64 + mi * 16 + (lane & 15)) * BK +
                                             (((ks * 4 + hi) ^ key) * 8)];
#pragma unroll
            for (int ni = 0; ni < 4; ++ni)
                bfr[ni] = *(const bf16x8*)&Bs[(wn * 64 + ni * 16 + (lane & 15)) * BK +
                                              (((ks * 4 + hi) ^ key) * 8)];
#pragma unroll
            for (int mi = 0; mi < 4; ++mi)
#pragma unroll
                for (int ni = 0; ni < 4; ++ni)
                    acc[mi][ni] = __builtin_amdgcn_mfma_f32_16x16x32_bf16(
                        af[mi], bfr[ni], acc[mi][ni], 0, 0, 0);
        }
        __syncthreads();
    }

    // epilogue: C/D layout col=lane&15, row=hi*4+reg
    if (STATS) {
        if (tid < 128) { smsum[tid] = 0.f; smsq[tid] = 0.f; }
        __syncthreads();
    }
    const int col0 = nbase + wn * 64 + (lane & 15);
    const long long row00 = rbase + wm * 64 + hi * 4;
#pragma unroll
    for (int ni = 0; ni < 4; ++ni) {
        int col = col0 + ni * 16;
        float bv = bias[col];
        float s = 0.f, q = 0.f;
#pragma unroll
        for (int mi = 0; mi < 4; ++mi) {
            long long r0 = row00 + mi * 16;
#pragma unroll
            for (int r = 0; r < 4; ++r) {
                float v = acc[mi][ni][r] + bv;
                if (RELU) v = fmaxf(v, 0.f);
                C[(r0 + r) * NH + col] = __float2bfloat16(v);
                if (STATS && (r0 + r) < NN) { s += v; q += v * v; }
            }
        }
        if (STATS) {
            s += __shfl_xor(s, 16); s += __shfl_xor(s, 32);
            q += __shfl_xor(q, 16); q += __shfl_xor(q, 32);
            if (lane < 16) {
                atomicAdd(&smsum[wn * 64 + ni * 16 + lane], s);
                atomicAdd(&smsq[wn * 64 + ni * 16 + lane], q);
            }
        }
    }
    if (STATS) {
        __syncthreads();
        if (tid < 128) {
            partial[blockIdx.x * 1024 + nbase + tid] = smsum[tid];
            partial[blockIdx.x * 1024 + 512 + nbase + tid] = smsq[tid];
        }
    }
}

// reduce per-block partials: stats[j] = sum_mb partial[mb*1024 + j], j<1024
__global__ __launch_bounds__(256) void stats_reduce(const float* __restrict__ partial,
                                                    float* __restrict__ stats) {
    int j = blockIdx.x * 256 + threadIdx.x;   // 0..1023
    float s = 0.f;
    for (int mb = 0; mb < MB; ++mb) s += partial[mb * 1024 + j];
    stats[j] = s;
}

// BN(train stats) + ReLU + classifier fused; bf16 h2, per-lane register params
__global__ __launch_bounds__(256) void bn_cls(const __hip_bfloat16* __restrict__ h2b,
                                              const float* __restrict__ stats,
                                              const float* __restrict__ gamma,
                                              const float* __restrict__ beta,
                                              const float* __restrict__ Wc,
                                              const float* __restrict__ bc,
                                              float* __restrict__ out) {
    int tid = threadIdx.x;
    int lane = tid & 63;
    int k0 = lane * 8;
    float sc[8], sh[8], w0[8], w1[8];
#pragma unroll
    for (int j = 0; j < 8; ++j) {
        int k = k0 + j;
        float mean = stats[k] * (1.0f / NN);
        float var = stats[512 + k] * (1.0f / NN) - mean * mean;
        float rs = rsqrtf(var + 1e-5f);
        float s = gamma[k] * rs;
        sc[j] = s;
        sh[j] = beta[k] - mean * s;
        w0[j] = Wc[2 * k];
        w1[j] = Wc[2 * k + 1];
    }
    float bc0 = bc[0], bc1 = bc[1];
    int wid = blockIdx.x * 4 + (tid >> 6);
    int nw = gridDim.x * 4;
    for (int row = wid; row < NN; row += nw) {
        bf16x8 v8 = *(const bf16x8*)&h2b[(long long)row * NH + k0];
        float a0 = 0.f, a1 = 0.f;
#pragma unroll
        for (int j = 0; j < 8; ++j) {
            float v = __bfloat162float(((const __hip_bfloat16*)&v8)[j]);
            float hn = fmaxf(fmaf(v, sc[j], sh[j]), 0.f);
            a0 = fmaf(hn, w0[j], a0);
            a1 = fmaf(hn, w1[j], a1);
        }
#pragma unroll
        for (int off = 32; off; off >>= 1) {
            a0 += __shfl_xor(a0, off);
            a1 += __shfl_xor(a1, off);
        }
        if (lane == 0) {
            out[(long long)row * 2 + 0] = a0 + bc0;
            out[(long long)row * 2 + 1] = a1 + bc1;
        }
    }
}

// ---------------------------------------------------------------------------
extern "C" void kernel_launch(void* const* d_in, const int* in_sizes, int n_in,
                              void* d_out, int out_size, void* d_ws, size_t ws_size,
                              hipStream_t stream) {
    const float* x     = (const float*)d_in[0];
    const void*  ei    = d_in[1];
    const float* W1    = (const float*)d_in[2];
    const float* b1    = (const float*)d_in[3];
    const float* W2    = (const float*)d_in[4];
    const float* b2    = (const float*)d_in[5];
    const float* gamma = (const float*)d_in[6];
    const float* beta  = (const float*)d_in[7];
    const float* Wc    = (const float*)d_in[8];
    const float* bc    = (const float*)d_in[9];
    float* out = (float*)d_out;

    // workspace carve-up (256B aligned)
    char* base = (char*)d_ws;
    size_t o = 0;
    auto alloc = [&](size_t bytes) {
        char* p = base + o;
        o = (o + bytes + 255) & ~(size_t)255;
        return p;
    };
    __hip_bfloat16* h0b     = (__hip_bfloat16*)alloc((size_t)MP * NF * 2);
    __hip_bfloat16* h1b     = (__hip_bfloat16*)alloc((size_t)MP * NH * 2);
    __hip_bfloat16* h2b     = (__hip_bfloat16*)alloc((size_t)MP * NH * 2);
    __hip_bfloat16* w1t     = (__hip_bfloat16*)alloc((size_t)NH * NF * 2);
    __hip_bfloat16* w2t     = (__hip_bfloat16*)alloc((size_t)NH * NH * 2);
    int*            deg     = (int*)alloc((size_t)NN * 4);
    int*            rowptr  = (int*)alloc((size_t)(NN + 1) * 4);
    int*            cursor  = (int*)alloc((size_t)NN * 4);
    int*            csr     = (int*)alloc((size_t)NE * 4);
    int*            bsum    = (int*)alloc((size_t)NB * 4);
    int*            boff    = (int*)alloc((size_t)NB * 4);
    float*          partial = (float*)alloc((size_t)MB * 1024 * 4);
    float*          stats   = (float*)alloc(1024 * 4);
    int*            flag    = (int*)alloc(256);

    hipMemsetAsync(deg, 0, (size_t)NN * 4, stream);
    detect_idx<<<1, 1, 0, stream>>>((const int*)ei, flag);

    // CSR build + gather
    edge_hist<<<(NE + 255) / 256, 256, 0, stream>>>(ei, flag, deg);
    scan_local<<<NB, 256, 0, stream>>>(deg, rowptr, bsum);
    scan_bsum<<<1, 256, 0, stream>>>(bsum, boff);
    scan_add<<<NB, 256, 0, stream>>>(rowptr, boff, cursor);
    edge_fill<<<(NE + 255) / 256, 256, 0, stream>>>(ei, flag, cursor, csr);
    gather<<<(MP * 16 + 255) / 256, 256, 0, stream>>>(x, rowptr, csr, h0b);

    cvt_wt<<<(NF * NH + 255) / 256, 256, 0, stream>>>(W1, w1t, NF, NH);
    cvt_wt<<<(NH * NH + 255) / 256, 256, 0, stream>>>(W2, w2t, NH, NH);

    // both GEMMs: grid (MB, 4) for full occupancy; GEMM2 fuses BN stats
    dim3 g1(MB, 4);
    gemm_mfma<NF, true, false><<<g1, 256, 0, stream>>>(h0b, w1t, b1, h1b, nullptr);
    gemm_mfma<NH, false, true><<<g1, 256, 0, stream>>>(h1b, w2t, b2, h2b, partial);

    stats_reduce<<<4, 256, 0, stream>>>(partial, stats);
    bn_cls<<<512, 256, 0, stream>>>(h2b, stats, gamma, beta, Wc, bc, out);
}

// Round 7
// 239.625 us; speedup vs baseline: 1.6563x; 1.0460x over previous
//
#include <hip/hip_runtime.h>
#include <hip/hip_bf16.h>

#define NN 50000      // nodes
#define MP 50176      // padded nodes (392 * 128)
#define NF 64         // features
#define NH 512        // hidden
#define NE 800000     // edges
#define NB 196        // scan blocks = ceil(NN/256)
#define MB 392        // M blocks = MP/128
#define GRID (MB * 4) // 1568 = 8 * 196
#define CPX (GRID / 8)

typedef __attribute__((ext_vector_type(8))) short bf16x8;
typedef __attribute__((ext_vector_type(4))) float f32x4;

#define GLOAD16(g, l)                                                        \
    __builtin_amdgcn_global_load_lds(                                        \
        (const __attribute__((address_space(1))) unsigned int*)(g),          \
        (__attribute__((address_space(3))) unsigned int*)(l), 16, 0, 0)

// ---------------------------------------------------------------------------
// detect whether edge_index is int64 (high dwords all zero) or int32
__global__ void detect_idx(const int* __restrict__ ei, int* __restrict__ flag) {
    if (threadIdx.x == 0 && blockIdx.x == 0) {
        int any = 0;
        for (int i = 0; i < 32; ++i) any |= ei[2 * i + 1];
        *flag = (any == 0) ? 1 : 0;   // 1 => int64 layout
    }
}

// ---------------------------------------------------------------------------
// CSR build: histogram of dst
__global__ __launch_bounds__(256) void edge_hist(const void* __restrict__ eiv,
                                                 const int* __restrict__ flag,
                                                 int* __restrict__ deg) {
    int e = blockIdx.x * 256 + threadIdx.x;
    if (e >= NE) return;
    int dst = *flag ? (int)((const long long*)eiv)[NE + e]
                    : ((const int*)eiv)[NE + e];
    atomicAdd(&deg[dst], 1);
}

// parallel scan step 1: per-block exclusive prefix + block sums
__global__ __launch_bounds__(256) void scan_local(const int* __restrict__ deg,
                                                  int* __restrict__ rowptr,
                                                  int* __restrict__ bsum) {
    __shared__ int sm[256];
    int tid = threadIdx.x;
    int i = blockIdx.x * 256 + tid;
    int v = (i < NN) ? deg[i] : 0;
    sm[tid] = v;
    __syncthreads();
    int acc = v;
#pragma unroll
    for (int off = 1; off < 256; off <<= 1) {
        int t = (tid >= off) ? sm[tid - off] : 0;
        __syncthreads();
        acc += t;
        sm[tid] = acc;
        __syncthreads();
    }
    if (i < NN) rowptr[i] = acc - v;           // local exclusive
    if (tid == 255) bsum[blockIdx.x] = acc;    // block total
}

// parallel scan step 2: exclusive scan of the NB block sums (1 block)
__global__ __launch_bounds__(256) void scan_bsum(const int* __restrict__ bsum,
                                                 int* __restrict__ boff) {
    __shared__ int sm[256];
    int tid = threadIdx.x;
    int v = (tid < NB) ? bsum[tid] : 0;
    sm[tid] = v;
    __syncthreads();
    int acc = v;
#pragma unroll
    for (int off = 1; off < 256; off <<= 1) {
        int t = (tid >= off) ? sm[tid - off] : 0;
        __syncthreads();
        acc += t;
        sm[tid] = acc;
        __syncthreads();
    }
    if (tid < NB) boff[tid] = acc - v;         // exclusive
}

// parallel scan step 3: add block offsets, emit rowptr & cursor
__global__ __launch_bounds__(256) void scan_add(int* __restrict__ rowptr,
                                                const int* __restrict__ boff,
                                                int* __restrict__ cursor) {
    int i = blockIdx.x * 256 + threadIdx.x;
    if (i < NN) {
        int r = rowptr[i] + boff[blockIdx.x];
        rowptr[i] = r;
        cursor[i] = r;
    }
    if (i == 0) rowptr[NN] = NE;   // total is the edge count by construction
}

// scatter edge sources into CSR slots
__global__ __launch_bounds__(256) void edge_fill(const void* __restrict__ eiv,
                                                 const int* __restrict__ flag,
                                                 int* __restrict__ cursor,
                                                 int* __restrict__ csr) {
    int e = blockIdx.x * 256 + threadIdx.x;
    if (e >= NE) return;
    int src, dst;
    if (*flag) {
        const long long* ei = (const long long*)eiv;
        src = (int)ei[e];
        dst = (int)ei[NE + e];
    } else {
        const int* ei = (const int*)eiv;
        src = ei[e];
        dst = ei[NE + e];
    }
    int pos = atomicAdd(&cursor[dst], 1);
    csr[pos] = src;
}

// gather-sum: h0b[n] = bf16( x[n] + sum_{s in N(n)} x[s] ), padded rows zero.
__global__ __launch_bounds__(256) void gather(const float* __restrict__ x,
                                              const int* __restrict__ rowptr,
                                              const int* __restrict__ csr,
                                              __hip_bfloat16* __restrict__ h0b) {
    int t = blockIdx.x * 256 + threadIdx.x;
    int n = t >> 4;
    int sub = t & 15;
    if (n >= MP) return;
    union { ushort4 u; __hip_bfloat16 h[4]; } o;
    if (n >= NN) {
        o.u = make_ushort4(0, 0, 0, 0);
        *(ushort4*)&h0b[(long long)n * NF + sub * 4] = o.u;
        return;
    }
    float4 acc = *(const float4*)&x[(long long)n * NF + sub * 4];
    int e0 = rowptr[n], e1 = rowptr[n + 1];
    for (int e = e0; e < e1; ++e) {
        int s = csr[e];
        float4 v = *(const float4*)&x[(long long)s * NF + sub * 4];
        acc.x += v.x; acc.y += v.y; acc.z += v.z; acc.w += v.w;
    }
    o.h[0] = __float2bfloat16(acc.x);
    o.h[1] = __float2bfloat16(acc.y);
    o.h[2] = __float2bfloat16(acc.z);
    o.h[3] = __float2bfloat16(acc.w);
    *(ushort4*)&h0b[(long long)n * NF + sub * 4] = o.u;
}

// W [K][N] fp32 -> WT [N][K] bf16
__global__ __launch_bounds__(256) void cvt_wt(const float* __restrict__ W,
                                              __hip_bfloat16* __restrict__ WT,
                                              int K, int N) {
    int t = blockIdx.x * 256 + threadIdx.x;
    if (t >= K * N) return;
    int n = t % N, k = t / N;
    WT[n * K + k] = __float2bfloat16(W[t]);
}

// ---------------------------------------------------------------------------
// bf16 MFMA GEMM, LDS XOR-swizzled (conflict-free), 1D grid with XCD-chunked
// bijective block swizzle: xcd = orig&7 owns mbs [xcd*49, xcd*49+49), all 4
// nb's of an mb dispatch onto the SAME XCD -> A-tile L2 reuse.
// Optional fused per-column stats into partial[mb*1024 + col / +512].
// LDS = exactly 32 KiB (stats scratch aliases As after the K-loop).
template <int K, bool RELU, bool STATS>
__global__ __launch_bounds__(256) void gemm_mfma(const __hip_bfloat16* __restrict__ A,
                                                 const __hip_bfloat16* __restrict__ BT,
                                                 const float* __restrict__ bias,
                                                 __hip_bfloat16* __restrict__ C,
                                                 float* __restrict__ partial) {
    constexpr int BK = 64;
    __shared__ __align__(16) char smem[32768];
    __hip_bfloat16* As = (__hip_bfloat16*)smem;
    __hip_bfloat16* Bs = (__hip_bfloat16*)(smem + 16384);
    float* smsum = (float*)smem;            // aliases As (dead after K-loop)
    float* smsq  = (float*)(smem + 2048);

    // XCD-chunked bijective swizzle (grid = 1568 = 8 * 196)
    const int orig = blockIdx.x;
    const int L = (orig & 7) * CPX + (orig >> 3);
    const int mb = L >> 2, nb = L & 3;

    const int tid = threadIdx.x;
    const int lane = tid & 63;
    const int w = tid >> 6;          // wave 0..3
    const int wm = w >> 1, wn = w & 1;
    const long long rbase = (long long)mb * 128;
    const int nbase = nb * 128;
    const int r8  = lane >> 3;            // stage row within 8-row group
    const int swc = (lane & 7) ^ r8;      // pre-swizzled global chunk (rule #21)
    const int key = lane & 7;             // read-side swizzle key
    const int hi  = lane >> 4;

    f32x4 acc[4][4];
#pragma unroll
    for (int i = 0; i < 4; ++i)
#pragma unroll
        for (int j = 0; j < 4; ++j) acc[i][j] = (f32x4){0.f, 0.f, 0.f, 0.f};

    for (int kb = 0; kb < K; kb += BK) {
        const __hip_bfloat16* ga =
            A + (rbase + w * 32 + r8) * (long long)K + kb + swc * 8;
        const __hip_bfloat16* gb =
            BT + (long long)(nbase + w * 32 + r8) * K + kb + swc * 8;
        __hip_bfloat16* la = As + (w * 32) * BK;
        __hip_bfloat16* lb = Bs + (w * 32) * BK;
#pragma unroll
        for (int t = 0; t < 4; ++t) {
            GLOAD16(ga + (long long)t * 8 * K, la + t * 8 * BK);
            GLOAD16(gb + (long long)t * 8 * K, lb + t * 8 * BK);
        }
        __syncthreads();

#pragma unroll
        for (int ks = 0; ks < 2; ++ks) {
            bf16x8 af[4], bfr[4];
#pragma unroll
            for (int mi = 0; mi < 4; ++mi)
                af[mi] = *(const bf16x8*)&As[(wm * 64 + mi * 16 + (lane & 15)) * BK +
                                             (((ks * 4 + hi) ^ key) * 8)];
#pragma unroll
            for (int ni = 0; ni < 4; ++ni)
                bfr[ni] = *(const bf16x8*)&Bs[(wn * 64 + ni * 16 + (lane & 15)) * BK +
                                              (((ks * 4 + hi) ^ key) * 8)];
#pragma unroll
            for (int mi = 0; mi < 4; ++mi)
#pragma unroll
                for (int ni = 0; ni < 4; ++ni)
                    acc[mi][ni] = __builtin_amdgcn_mfma_f32_16x16x32_bf16(
                        af[mi], bfr[ni], acc[mi][ni], 0, 0, 0);
        }
        __syncthreads();
    }

    // epilogue: C/D layout col=lane&15, row=hi*4+reg
    if (STATS) {
        if (tid < 128) { smsum[tid] = 0.f; smsq[tid] = 0.f; }
        __syncthreads();
    }
    const int col0 = nbase + wn * 64 + (lane & 15);
    const long long row00 = rbase + wm * 64 + hi * 4;
#pragma unroll
    for (int ni = 0; ni < 4; ++ni) {
        int col = col0 + ni * 16;
        float bv = bias[col];
        float s = 0.f, q = 0.f;
#pragma unroll
        for (int mi = 0; mi < 4; ++mi) {
            long long r0 = row00 + mi * 16;
#pragma unroll
            for (int r = 0; r < 4; ++r) {
                float v = acc[mi][ni][r] + bv;
                if (RELU) v = fmaxf(v, 0.f);
                C[(r0 + r) * NH + col] = __float2bfloat16(v);
                if (STATS && (r0 + r) < NN) { s += v; q += v * v; }
            }
        }
        if (STATS) {
            s += __shfl_xor(s, 16); s += __shfl_xor(s, 32);
            q += __shfl_xor(q, 16); q += __shfl_xor(q, 32);
            if (lane < 16) {
                atomicAdd(&smsum[wn * 64 + ni * 16 + lane], s);
                atomicAdd(&smsq[wn * 64 + ni * 16 + lane], q);
            }
        }
    }
    if (STATS) {
        __syncthreads();
        if (tid < 128) {
            partial[mb * 1024 + nbase + tid] = smsum[tid];
            partial[mb * 1024 + 512 + nbase + tid] = smsq[tid];
        }
    }
}

// reduce per-block partials: stats[j] = sum_mb partial[mb*1024 + j], j<1024
__global__ __launch_bounds__(256) void stats_reduce(const float* __restrict__ partial,
                                                    float* __restrict__ stats) {
    int j = blockIdx.x * 256 + threadIdx.x;   // 0..1023
    float s = 0.f;
    for (int mb = 0; mb < MB; ++mb) s += partial[mb * 1024 + j];
    stats[j] = s;
}

// BN(train stats) + ReLU + classifier fused; bf16 h2, per-lane register params
__global__ __launch_bounds__(256) void bn_cls(const __hip_bfloat16* __restrict__ h2b,
                                              const float* __restrict__ stats,
                                              const float* __restrict__ gamma,
                                              const float* __restrict__ beta,
                                              const float* __restrict__ Wc,
                                              const float* __restrict__ bc,
                                              float* __restrict__ out) {
    int tid = threadIdx.x;
    int lane = tid & 63;
    int k0 = lane * 8;
    float sc[8], sh[8], w0[8], w1[8];
#pragma unroll
    for (int j = 0; j < 8; ++j) {
        int k = k0 + j;
        float mean = stats[k] * (1.0f / NN);
        float var = stats[512 + k] * (1.0f / NN) - mean * mean;
        float rs = rsqrtf(var + 1e-5f);
        float s = gamma[k] * rs;
        sc[j] = s;
        sh[j] = beta[k] - mean * s;
        w0[j] = Wc[2 * k];
        w1[j] = Wc[2 * k + 1];
    }
    float bc0 = bc[0], bc1 = bc[1];
    int wid = blockIdx.x * 4 + (tid >> 6);
    int nw = gridDim.x * 4;
    for (int row = wid; row < NN; row += nw) {
        bf16x8 v8 = *(const bf16x8*)&h2b[(long long)row * NH + k0];
        float a0 = 0.f, a1 = 0.f;
#pragma unroll
        for (int j = 0; j < 8; ++j) {
            float v = __bfloat162float(((const __hip_bfloat16*)&v8)[j]);
            float hn = fmaxf(fmaf(v, sc[j], sh[j]), 0.f);
            a0 = fmaf(hn, w0[j], a0);
            a1 = fmaf(hn, w1[j], a1);
        }
#pragma unroll
        for (int off = 32; off; off >>= 1) {
            a0 += __shfl_xor(a0, off);
            a1 += __shfl_xor(a1, off);
        }
        if (lane == 0) {
            out[(long long)row * 2 + 0] = a0 + bc0;
            out[(long long)row * 2 + 1] = a1 + bc1;
        }
    }
}

// ---------------------------------------------------------------------------
extern "C" void kernel_launch(void* const* d_in, const int* in_sizes, int n_in,
                              void* d_out, int out_size, void* d_ws, size_t ws_size,
                              hipStream_t stream) {
    const float* x     = (const float*)d_in[0];
    const void*  ei    = d_in[1];
    const float* W1    = (const float*)d_in[2];
    const float* b1    = (const float*)d_in[3];
    const float* W2    = (const float*)d_in[4];
    const float* b2    = (const float*)d_in[5];
    const float* gamma = (const float*)d_in[6];
    const float* beta  = (const float*)d_in[7];
    const float* Wc    = (const float*)d_in[8];
    const float* bc    = (const float*)d_in[9];
    float* out = (float*)d_out;

    // workspace carve-up (256B aligned)
    char* base = (char*)d_ws;
    size_t o = 0;
    auto alloc = [&](size_t bytes) {
        char* p = base + o;
        o = (o + bytes + 255) & ~(size_t)255;
        return p;
    };
    __hip_bfloat16* h0b     = (__hip_bfloat16*)alloc((size_t)MP * NF * 2);
    __hip_bfloat16* h1b     = (__hip_bfloat16*)alloc((size_t)MP * NH * 2);
    __hip_bfloat16* h2b     = (__hip_bfloat16*)alloc((size_t)MP * NH * 2);
    __hip_bfloat16* w1t     = (__hip_bfloat16*)alloc((size_t)NH * NF * 2);
    __hip_bfloat16* w2t     = (__hip_bfloat16*)alloc((size_t)NH * NH * 2);
    int*            deg     = (int*)alloc((size_t)NN * 4);
    int*            rowptr  = (int*)alloc((size_t)(NN + 1) * 4);
    int*            cursor  = (int*)alloc((size_t)NN * 4);
    int*            csr     = (int*)alloc((size_t)NE * 4);
    int*            bsum    = (int*)alloc((size_t)NB * 4);
    int*            boff    = (int*)alloc((size_t)NB * 4);
    float*          partial = (float*)alloc((size_t)MB * 1024 * 4);
    float*          stats   = (float*)alloc(1024 * 4);
    int*            flag    = (int*)alloc(256);

    hipMemsetAsync(deg, 0, (size_t)NN * 4, stream);
    detect_idx<<<1, 1, 0, stream>>>((const int*)ei, flag);

    // CSR build + gather
    edge_hist<<<(NE + 255) / 256, 256, 0, stream>>>(ei, flag, deg);
    scan_local<<<NB, 256, 0, stream>>>(deg, rowptr, bsum);
    scan_bsum<<<1, 256, 0, stream>>>(bsum, boff);
    scan_add<<<NB, 256, 0, stream>>>(rowptr, boff, cursor);
    edge_fill<<<(NE + 255) / 256, 256, 0, stream>>>(ei, flag, cursor, csr);
    gather<<<(MP * 16 + 255) / 256, 256, 0, stream>>>(x, rowptr, csr, h0b);

    cvt_wt<<<(NF * NH + 255) / 256, 256, 0, stream>>>(W1, w1t, NF, NH);
    cvt_wt<<<(NH * NH + 255) / 256, 256, 0, stream>>>(W2, w2t, NH, NH);

    // both GEMMs: 1D grid 1568 with XCD-chunked swizzle; GEMM2 fuses BN stats
    gemm_mfma<NF, true, false><<<GRID, 256, 0, stream>>>(h0b, w1t, b1, h1b, nullptr);
    gemm_mfma<NH, false, true><<<GRID, 256, 0, stream>>>(h1b, w2t, b2, h2b, partial);

    stats_reduce<<<4, 256, 0, stream>>>(partial, stats);
    bn_cls<<<512, 256, 0, stream>>>(h2b, stats, gamma, beta, Wc, bc, out);
}